// Round 19
// baseline (208.778 us; speedup 1.0000x reference)
//
#include <hip/hip_runtime.h>
#include <stdint.h>

// VectorQuantizer — f32 I/O confirmed. d_in[0]=z [16384,64], d_in[1]=e [8192,64];
// d_out f32: [z_q 16384*64][idx-as-float 16384]. d_ws = 256MB confirmed.
//
// FROZEN exact numerics (eval path only):
//   sz,se: scalar pairwise-8; c: 4 lanes (k mod 4), mul/add separately rounded,
//   16-chunks ascending, reversed sub-blocks (+12,+8,+4,+0), hadd (q0+q1)+(q2+q3);
//   A=fl(sz+se); d=fl(A-2c); argmin strict-<, first (smallest) index wins.
//
// Round-19: eval v11 — OCCUPANCY fix. r16/r18 both ~39.5us with different inner
// loops; VALU-busy ~15us vs dur 39.6 and Occ 15% => latency-exposed at the
// 4 waves/SIMD cap imposed by the 34KB LDS tile. Fix: HALF-CHUNK tiles (64
// j-rows, 17.4KB) via blockIdx.y -> 8 blocks/CU; acc halves to acc[4][4]
// (~50 live VGPRs) so amdgpu_waves_per_eu(6) holds without spills -> 6-8
// waves/SIMD. Cross-half combine = the verified order-invariant atomicMin
// (disjoint j-ranges; equal d -> smaller j). Inner loop unchanged from v10.

#define NROWS 16384
#define NE    8192
#define D     64
#define BN    128
#define NCH   (NE / BN)     // 64
#define BAND  1.25e-4f
#define CAND_CAP 16384
#define EVG   16            // item-groups per (chunk, half)
#define ELS   68            // LDS row stride (floats): 272B, 16B-aligned, b128-optimal

typedef __attribute__((ext_vector_type(8))) short short8;
typedef __attribute__((ext_vector_type(4))) float f32x4;

__device__ __forceinline__ uint32_t bf16rn(float f) {
    union { float f; uint32_t u; } c; c.f = f;
    return (c.u + 0x7FFFu + ((c.u >> 16) & 1u)) >> 16;
}
__device__ __forceinline__ uint32_t pk2(float lo, float hi) {
    return bf16rn(lo) | (bf16rn(hi) << 16);
}
#define RL(v, l) __uint_as_float(__builtin_amdgcn_readlane(__float_as_uint(v), (l)))

// ---------- phase 0: fused convert + coalesced exact prep (verified) ----------
__global__ __launch_bounds__(256)
void vq_convert_prep(const float* __restrict__ z, const float* __restrict__ e,
                     uint32_t* __restrict__ zb, uint32_t* __restrict__ eb,
                     float* __restrict__ sz_arr, float* __restrict__ se_arr)
{
    if (blockIdx.x < 768) {
        const int i = blockIdx.x * 256 + threadIdx.x;
        const int nz = NROWS * D / 8;
        const int ne = NE * D / 8;
        if (i < nz) {
            const float4 a = ((const float4*)z)[i * 2];
            const float4 b = ((const float4*)z)[i * 2 + 1];
            uint4 o; o.x = pk2(a.x, a.y); o.y = pk2(a.z, a.w);
            o.z = pk2(b.x, b.y); o.w = pk2(b.z, b.w);
            ((uint4*)zb)[i] = o;
        } else if (i < nz + ne) {
            const int k = i - nz;
            const float4 a = ((const float4*)e)[k * 2];
            const float4 b = ((const float4*)e)[k * 2 + 1];
            uint4 o; o.x = pk2(a.x, a.y); o.y = pk2(a.z, a.w);
            o.z = pk2(b.x, b.y); o.w = pk2(b.z, b.w);
            ((uint4*)eb)[k] = o;
        }
    } else {
        const int pb   = blockIdx.x - 768;
        const int wave = threadIdx.x >> 6, lane = threadIdx.x & 63;
        const int g    = lane & 7;
        const int grow = pb * 32 + wave * 8 + (lane >> 3);
        const float* src = (grow < NROWS) ? z + (size_t)grow * D
                                          : e + (size_t)(grow - NROWS) * D;
        float acc = 0.f;
        #pragma unroll
        for (int i = 0; i < 8; ++i) {
            const float x = src[i * 8 + g];
            acc = __fadd_rn(acc, __fmul_rn(x, x));
        }
        const float s1 = __fadd_rn(acc, __shfl_xor(acc, 1, 64));
        const float s2 = __fadd_rn(s1,  __shfl_xor(s1, 2, 64));
        const float s4 = __fadd_rn(s2,  __shfl_xor(s2, 4, 64));
        if (g == 0) {
            if (grow < NROWS) sz_arr[grow] = s4;
            else              se_arr[grow - NROWS] = s4;
        }
    }
}

// ---------- phase 1: MFMA GEMM + per-(row,chunk) max (verified, unchanged) ----------
__global__ __launch_bounds__(256)
void vq_scan_mfma(const uint16_t* __restrict__ zb, const uint16_t* __restrict__ eb,
                  float* __restrict__ cmax)
{
    __shared__ uint16_t elds[BN][72];
    __shared__ float    rmld[4][64][20];

    const int tid  = threadIdx.x;
    const int lane = tid & 63, w = tid >> 6;
    const int mb   = blockIdx.x >> 5;
    const int jb   = blockIdx.x & 31;
    const int row0 = mb * 256 + w * 64;
    const int l15  = lane & 15, l4 = lane >> 4;

    short8 af[4][2];
    #pragma unroll
    for (int m = 0; m < 4; ++m)
        #pragma unroll
        for (int h = 0; h < 2; ++h)
            af[m][h] = *(const short8*)(zb + (size_t)(row0 + m * 16 + l15) * D + h * 32 + l4 * 8);

    const f32x4 z4 = {0.f, 0.f, 0.f, 0.f};

    #pragma unroll 1
    for (int c = 0; c < 2; ++c) {
        const int j0 = jb * 256 + c * BN;
        {
            const int srow = tid >> 1, shalf = tid & 1;
            const uint16_t* sp = eb + (size_t)(j0 + srow) * D + shalf * 32;
            uint16_t* dp = &elds[srow][shalf * 32];
            #pragma unroll
            for (int q = 0; q < 4; ++q)
                *(short8*)(dp + q * 8) = *(const short8*)(sp + q * 8);
        }
        __syncthreads();

        f32x4 rm[4];
        #pragma unroll
        for (int m = 0; m < 4; ++m) rm[m] = {-3.0e38f, -3.0e38f, -3.0e38f, -3.0e38f};

        #pragma unroll 1
        for (int n = 0; n < 8; ++n) {
            const uint16_t* bp = &elds[n * 16 + l15][l4 * 8];
            const short8 b0 = *(const short8*)(bp);
            const short8 b1 = *(const short8*)(bp + 32);
            #pragma unroll
            for (int m = 0; m < 4; ++m) {
                f32x4 acc = __builtin_amdgcn_mfma_f32_16x16x32_bf16(af[m][0], b0, z4, 0, 0, 0);
                acc = __builtin_amdgcn_mfma_f32_16x16x32_bf16(af[m][1], b1, acc, 0, 0, 0);
                #pragma unroll
                for (int r = 0; r < 4; ++r) rm[m][r] = fmaxf(rm[m][r], acc[r]);
            }
        }

        #pragma unroll
        for (int m = 0; m < 4; ++m)
            *(f32x4*)&rmld[w][lane][m * 4] = rm[m];
        const int r  = lane;
        const int mm = r >> 4, rg = r & 3, lg = ((r & 15) >> 2) * 16;
        float v = rmld[w][lg][mm * 4 + rg];
        #pragma unroll
        for (int i = 1; i < 16; ++i) v = fmaxf(v, rmld[w][lg + i][mm * 4 + rg]);
        cmax[(size_t)(row0 + r) * NCH + (jb * 2 + c)] = v;
        __syncthreads();
    }
}

// ---------- phase 2a: band-select -> per-row bitmask (no atomics) ----------
__global__ __launch_bounds__(256)
void vq_select_mask(const float* __restrict__ cmax,
                    unsigned long long* __restrict__ mask,
                    unsigned long long* __restrict__ packed)
{
    const int lane = threadIdx.x & 63, w = threadIdx.x >> 6;
    const int row = blockIdx.x * 4 + w;

    const float ci = cmax[(size_t)row * NCH + lane];   // lane = chunk
    float cm = ci;
    #pragma unroll
    for (int o = 1; o < 64; o <<= 1) cm = fmaxf(cm, __shfl_xor(cm, o, 64));
    const unsigned long long m = __ballot(ci >= cm - BAND);
    if (lane == 0) { mask[row] = m; packed[row] = 0xFFFFFFFFFFFFFFFFull; }
}

// ---------- phase 2b: compaction (barrier-free, LDS atomic, unordered) ----------
__global__ __launch_bounds__(256)
void vq_compact(const unsigned long long* __restrict__ mask,
                int* __restrict__ cand, unsigned int* __restrict__ counts)
{
    __shared__ unsigned int cnt_lds;
    const int ch = blockIdx.x;
    const int t = threadIdx.x, lane = t & 63;
    if (t == 0) cnt_lds = 0;
    __syncthreads();

    #pragma unroll 1
    for (int r0 = 0; r0 < NROWS; r0 += 256) {
        const int row = r0 + t;
        const bool hit = (mask[row] >> ch) & 1ull;
        const unsigned long long b = __ballot(hit);
        unsigned int base = 0;
        if (lane == 0 && b) base = atomicAdd(&cnt_lds, (unsigned int)__popcll(b));
        base = (unsigned int)__shfl((int)base, 0, 64);
        if (hit) {
            const unsigned int rank = (unsigned int)__popcll(b & ((1ull << lane) - 1ull));
            cand[(size_t)ch * CAND_CAP + base + rank] = row;
        }
    }
    __syncthreads();
    if (t == 0) counts[ch] = cnt_lds;
}

// ---------- phase 2c: eval v11 — half-chunk LDS (17.4KB), 6-8 waves/SIMD ----------
__global__ __launch_bounds__(256)
__attribute__((amdgpu_waves_per_eu(6)))
void vq_eval(const float* __restrict__ z, const float* __restrict__ e,
             const float* __restrict__ sz_arr, const float* __restrict__ se_arr,
             const unsigned int* __restrict__ counts, const int* __restrict__ cand,
             unsigned long long* __restrict__ packed)
{
    __shared__ float el[64 * ELS];       // 17408 B: half-chunk (64 j-rows)

    const int ch   = blockIdx.x;         // 0..63
    const int half = blockIdx.y;         // 0..1
    const int grp  = blockIdx.z;         // 0..EVG-1
    const int t    = threadIdx.x, lane = t & 63, w = t >> 6;

    const unsigned int cnt = counts[ch];
    const int base0 = grp * 16;
    if ((unsigned int)base0 >= cnt) return;

    {   // stage half-chunk: 64 rows x 64 f, coalesced float4 -> b128 LDS writes
        const float4* src4 = (const float4*)(e + (size_t)(ch * BN + half * 64) * D);
        #pragma unroll
        for (int v = t; v < 64 * D / 4; v += 256) {
            const int row = v >> 4, c4 = (v & 15) << 2;
            *(float4*)&el[row * ELS + c4] = src4[v];
        }
    }
    __syncthreads();   // only barrier; el read-only afterwards

    const int j   = ch * BN + half * 64 + lane;   // this lane's codeword
    const float* e0 = &el[lane * ELS];
    const float se0 = se_arr[j];
    const int gsrc  = lane & 15;                  // granule this lane sources
    const int isrc  = lane >> 4;                  // item this lane sources (0..3)

    for (unsigned int s0 = (unsigned int)(base0 + w * 4); s0 < cnt; s0 += (unsigned int)EVG * 16u) {
        int rows[4]; float szs[4];
        #pragma unroll
        for (int it = 0; it < 4; ++it) {
            unsigned int si = s0 + it; if (si >= cnt) si = cnt - 1;   // dup: idempotent
            rows[it] = cand[(size_t)ch * CAND_CAP + si];   // uniform -> s_load
            szs[it]  = sz_arr[rows[it]];                   // uniform -> s_load
        }
        const float4 zf = *(const float4*)(z + (size_t)rows[isrc] * D + gsrc * 4);

        float acc[4][4];   // [item][q] — 16 static accumulators
        #pragma unroll
        for (int it = 0; it < 4; ++it)
            #pragma unroll
            for (int q = 0; q < 4; ++q) acc[it][q] = 0.f;

        // frozen order: cc ascending; granules +12,+8,+4,+0; q_i gets k===i mod 4
        #pragma unroll
        for (int cc = 0; cc < 4; ++cc) {
            #pragma unroll
            for (int sb = 3; sb >= 0; --sb) {
                const int b = cc * 16 + sb * 4;
                const int g = cc * 4 + sb;
                const float4 ef = *(const float4*)&e0[b];   // ds_read_b128
                #pragma unroll
                for (int it = 0; it < 4; ++it) {
                    const int sl = it * 16 + g;             // compile-time lane
                    acc[it][0] = __fadd_rn(acc[it][0], __fmul_rn(RL(zf.x, sl), ef.x));
                    acc[it][1] = __fadd_rn(acc[it][1], __fmul_rn(RL(zf.y, sl), ef.y));
                    acc[it][2] = __fadd_rn(acc[it][2], __fmul_rn(RL(zf.z, sl), ef.z));
                    acc[it][3] = __fadd_rn(acc[it][3], __fmul_rn(RL(zf.w, sl), ef.w));
                }
            }
        }

        #pragma unroll
        for (int it = 0; it < 4; ++it) {
            const float c = __fadd_rn(__fadd_rn(acc[it][0], acc[it][1]),
                                      __fadd_rn(acc[it][2], acc[it][3]));
            const float A = __fadd_rn(szs[it], se0);           // fl(sz + se)
            float d  = __fsub_rn(A, __fadd_rn(c, c));          // fl(A - 2c)
            int   bj = j;
            #pragma unroll
            for (int o = 1; o < 64; o <<= 1) {                 // argmin, first-index ties
                const float od = __shfl_xor(d, o, 64);
                const int   oj = __shfl_xor(bj, o, 64);
                if (od < d || (od == d && oj < bj)) { d = od; bj = oj; }
            }
            if (lane == 0) {
                const unsigned long long key =
                    ((unsigned long long)__float_as_uint(d) << 32) | (unsigned int)bj;
                atomicMin(packed + rows[it], key);   // d>0 -> monotone; order-invariant
            }
        }
    }
}

// ---------- phase 3: z_q + idx from packed ----------
__global__ __launch_bounds__(256)
void vq_zq(const float* __restrict__ z, const float* __restrict__ e,
           const unsigned long long* __restrict__ packed, float* __restrict__ out)
{
    const size_t m = (size_t)blockIdx.x * 256 + threadIdx.x;
    const int r = (int)(m >> 6), k = (int)(m & 63);
    const int sel = (int)(packed[r] & 0xFFFFFFFFull);
    const float zv = z[m];
    const float ev = e[(size_t)sel * D + k];
    out[m] = __fadd_rn(zv, __fsub_rn(ev, zv));
    if (k == 0) out[(size_t)NROWS * D + r] = (float)sel;
}

extern "C" void kernel_launch(void* const* d_in, const int* in_sizes, int n_in,
                              void* d_out, int out_size, void* d_ws, size_t ws_size,
                              hipStream_t stream)
{
    const float* z = (const float*)d_in[0];
    const float* e = (const float*)d_in[1];
    float* out = (float*)d_out;

    char* ws = (char*)d_ws;
    const size_t MB = 1024 * 1024, KB = 1024;
    uint16_t* zb               = (uint16_t*)(ws);                         // 0..2 MB
    uint16_t* eb               = (uint16_t*)(ws + 2 * MB);                // 2..3 MB
    float* cmaxb               = (float*)(ws + 3 * MB);                   // 3..7 MB
    float* sz_arr              = (float*)(ws + 7 * MB);                   // 64 KB
    float* se_arr              = (float*)(ws + 7 * MB + 64 * KB);         // 32 KB
    unsigned long long* mask   = (unsigned long long*)(ws + 7 * MB + 128 * KB); // 128 KB
    unsigned long long* packed = (unsigned long long*)(ws + 7 * MB + 256 * KB); // 128 KB
    unsigned int* counts       = (unsigned int*)(ws + 7 * MB + 384 * KB); // 256 B
    int* cand                  = (int*)(ws + 8 * MB);                     // 8..12 MB

    vq_convert_prep<<<dim3(1536),            dim3(256), 0, stream>>>(z, e, (uint32_t*)zb, (uint32_t*)eb, sz_arr, se_arr);
    vq_scan_mfma   <<<dim3(2048),            dim3(256), 0, stream>>>(zb, eb, cmaxb);
    vq_select_mask <<<dim3(NROWS / 4),       dim3(256), 0, stream>>>(cmaxb, mask, packed);
    vq_compact     <<<dim3(NCH),             dim3(256), 0, stream>>>(mask, cand, counts);
    vq_eval        <<<dim3(NCH, 2, EVG),     dim3(256), 0, stream>>>(z, e, sz_arr, se_arr, counts, cand, packed);
    vq_zq          <<<dim3(NROWS * D / 256), dim3(256), 0, stream>>>(z, e, packed, out);
}

// Round 20
// 113.249 us; speedup vs baseline: 1.8435x; 1.8435x over previous
//
#include <hip/hip_runtime.h>
#include <stdint.h>

// VectorQuantizer — f32 I/O confirmed. d_in[0]=z [16384,64], d_in[1]=e [8192,64];
// d_out f32: [z_q 16384*64][idx-as-float 16384]. d_ws = 256MB confirmed.
//
// FROZEN exact numerics (eval path only):
//   sz,se: scalar pairwise-8; c: 4 lanes (k mod 4), mul/add separately rounded,
//   16-chunks ascending, reversed sub-blocks (+12,+8,+4,+0), hadd (q0+q1)+(q2+q3);
//   A=fl(sz+se); d=fl(A-2c); argmin strict-<, first (smallest) index wins.
//
// Round-20: r19's waves_per_eu(6) FORCED VGPR<=40 -> acc spilled to scratch
// (FETCH 5.8MB -> 278MB, eval 150us). Occupancy mechanism itself validated
// (15->41%). Fix: keep half-chunk LDS (17.4KB -> LDS permits 8 blocks/CU),
// REMOVE the attribute — live set ~50 VGPR fits the 64-reg/8-wave budget the
// compiler targets naturally when LDS allows it (m69 steps at 64/128/256).
// Inner loop identical to the r18/r19-verified v10/v11 (4 items/pass, z via
// lane-distributed float4 + compile-time readlane, e via b128, frozen order,
// order-invariant atomicMin combine; dup-tail idempotent).

#define NROWS 16384
#define NE    8192
#define D     64
#define BN    128
#define NCH   (NE / BN)     // 64
#define BAND  1.25e-4f
#define CAND_CAP 16384
#define EVG   16            // item-groups per (chunk, half)
#define ELS   68            // LDS row stride (floats): 272B, 16B-aligned, b128-optimal

typedef __attribute__((ext_vector_type(8))) short short8;
typedef __attribute__((ext_vector_type(4))) float f32x4;

__device__ __forceinline__ uint32_t bf16rn(float f) {
    union { float f; uint32_t u; } c; c.f = f;
    return (c.u + 0x7FFFu + ((c.u >> 16) & 1u)) >> 16;
}
__device__ __forceinline__ uint32_t pk2(float lo, float hi) {
    return bf16rn(lo) | (bf16rn(hi) << 16);
}
#define RL(v, l) __uint_as_float(__builtin_amdgcn_readlane(__float_as_uint(v), (l)))

// ---------- phase 0: fused convert + coalesced exact prep (verified) ----------
__global__ __launch_bounds__(256)
void vq_convert_prep(const float* __restrict__ z, const float* __restrict__ e,
                     uint32_t* __restrict__ zb, uint32_t* __restrict__ eb,
                     float* __restrict__ sz_arr, float* __restrict__ se_arr)
{
    if (blockIdx.x < 768) {
        const int i = blockIdx.x * 256 + threadIdx.x;
        const int nz = NROWS * D / 8;
        const int ne = NE * D / 8;
        if (i < nz) {
            const float4 a = ((const float4*)z)[i * 2];
            const float4 b = ((const float4*)z)[i * 2 + 1];
            uint4 o; o.x = pk2(a.x, a.y); o.y = pk2(a.z, a.w);
            o.z = pk2(b.x, b.y); o.w = pk2(b.z, b.w);
            ((uint4*)zb)[i] = o;
        } else if (i < nz + ne) {
            const int k = i - nz;
            const float4 a = ((const float4*)e)[k * 2];
            const float4 b = ((const float4*)e)[k * 2 + 1];
            uint4 o; o.x = pk2(a.x, a.y); o.y = pk2(a.z, a.w);
            o.z = pk2(b.x, b.y); o.w = pk2(b.z, b.w);
            ((uint4*)eb)[k] = o;
        }
    } else {
        const int pb   = blockIdx.x - 768;
        const int wave = threadIdx.x >> 6, lane = threadIdx.x & 63;
        const int g    = lane & 7;
        const int grow = pb * 32 + wave * 8 + (lane >> 3);
        const float* src = (grow < NROWS) ? z + (size_t)grow * D
                                          : e + (size_t)(grow - NROWS) * D;
        float acc = 0.f;
        #pragma unroll
        for (int i = 0; i < 8; ++i) {
            const float x = src[i * 8 + g];
            acc = __fadd_rn(acc, __fmul_rn(x, x));
        }
        const float s1 = __fadd_rn(acc, __shfl_xor(acc, 1, 64));
        const float s2 = __fadd_rn(s1,  __shfl_xor(s1, 2, 64));
        const float s4 = __fadd_rn(s2,  __shfl_xor(s2, 4, 64));
        if (g == 0) {
            if (grow < NROWS) sz_arr[grow] = s4;
            else              se_arr[grow - NROWS] = s4;
        }
    }
}

// ---------- phase 1: MFMA GEMM + per-(row,chunk) max (verified, unchanged) ----------
__global__ __launch_bounds__(256)
void vq_scan_mfma(const uint16_t* __restrict__ zb, const uint16_t* __restrict__ eb,
                  float* __restrict__ cmax)
{
    __shared__ uint16_t elds[BN][72];
    __shared__ float    rmld[4][64][20];

    const int tid  = threadIdx.x;
    const int lane = tid & 63, w = tid >> 6;
    const int mb   = blockIdx.x >> 5;
    const int jb   = blockIdx.x & 31;
    const int row0 = mb * 256 + w * 64;
    const int l15  = lane & 15, l4 = lane >> 4;

    short8 af[4][2];
    #pragma unroll
    for (int m = 0; m < 4; ++m)
        #pragma unroll
        for (int h = 0; h < 2; ++h)
            af[m][h] = *(const short8*)(zb + (size_t)(row0 + m * 16 + l15) * D + h * 32 + l4 * 8);

    const f32x4 z4 = {0.f, 0.f, 0.f, 0.f};

    #pragma unroll 1
    for (int c = 0; c < 2; ++c) {
        const int j0 = jb * 256 + c * BN;
        {
            const int srow = tid >> 1, shalf = tid & 1;
            const uint16_t* sp = eb + (size_t)(j0 + srow) * D + shalf * 32;
            uint16_t* dp = &elds[srow][shalf * 32];
            #pragma unroll
            for (int q = 0; q < 4; ++q)
                *(short8*)(dp + q * 8) = *(const short8*)(sp + q * 8);
        }
        __syncthreads();

        f32x4 rm[4];
        #pragma unroll
        for (int m = 0; m < 4; ++m) rm[m] = {-3.0e38f, -3.0e38f, -3.0e38f, -3.0e38f};

        #pragma unroll 1
        for (int n = 0; n < 8; ++n) {
            const uint16_t* bp = &elds[n * 16 + l15][l4 * 8];
            const short8 b0 = *(const short8*)(bp);
            const short8 b1 = *(const short8*)(bp + 32);
            #pragma unroll
            for (int m = 0; m < 4; ++m) {
                f32x4 acc = __builtin_amdgcn_mfma_f32_16x16x32_bf16(af[m][0], b0, z4, 0, 0, 0);
                acc = __builtin_amdgcn_mfma_f32_16x16x32_bf16(af[m][1], b1, acc, 0, 0, 0);
                #pragma unroll
                for (int r = 0; r < 4; ++r) rm[m][r] = fmaxf(rm[m][r], acc[r]);
            }
        }

        #pragma unroll
        for (int m = 0; m < 4; ++m)
            *(f32x4*)&rmld[w][lane][m * 4] = rm[m];
        const int r  = lane;
        const int mm = r >> 4, rg = r & 3, lg = ((r & 15) >> 2) * 16;
        float v = rmld[w][lg][mm * 4 + rg];
        #pragma unroll
        for (int i = 1; i < 16; ++i) v = fmaxf(v, rmld[w][lg + i][mm * 4 + rg]);
        cmax[(size_t)(row0 + r) * NCH + (jb * 2 + c)] = v;
        __syncthreads();
    }
}

// ---------- phase 2a: band-select -> per-row bitmask (no atomics) ----------
__global__ __launch_bounds__(256)
void vq_select_mask(const float* __restrict__ cmax,
                    unsigned long long* __restrict__ mask,
                    unsigned long long* __restrict__ packed)
{
    const int lane = threadIdx.x & 63, w = threadIdx.x >> 6;
    const int row = blockIdx.x * 4 + w;

    const float ci = cmax[(size_t)row * NCH + lane];   // lane = chunk
    float cm = ci;
    #pragma unroll
    for (int o = 1; o < 64; o <<= 1) cm = fmaxf(cm, __shfl_xor(cm, o, 64));
    const unsigned long long m = __ballot(ci >= cm - BAND);
    if (lane == 0) { mask[row] = m; packed[row] = 0xFFFFFFFFFFFFFFFFull; }
}

// ---------- phase 2b: compaction (barrier-free, LDS atomic, unordered) ----------
__global__ __launch_bounds__(256)
void vq_compact(const unsigned long long* __restrict__ mask,
                int* __restrict__ cand, unsigned int* __restrict__ counts)
{
    __shared__ unsigned int cnt_lds;
    const int ch = blockIdx.x;
    const int t = threadIdx.x, lane = t & 63;
    if (t == 0) cnt_lds = 0;
    __syncthreads();

    #pragma unroll 1
    for (int r0 = 0; r0 < NROWS; r0 += 256) {
        const int row = r0 + t;
        const bool hit = (mask[row] >> ch) & 1ull;
        const unsigned long long b = __ballot(hit);
        unsigned int base = 0;
        if (lane == 0 && b) base = atomicAdd(&cnt_lds, (unsigned int)__popcll(b));
        base = (unsigned int)__shfl((int)base, 0, 64);
        if (hit) {
            const unsigned int rank = (unsigned int)__popcll(b & ((1ull << lane) - 1ull));
            cand[(size_t)ch * CAND_CAP + base + rank] = row;
        }
    }
    __syncthreads();
    if (t == 0) counts[ch] = cnt_lds;
}

// ---------- phase 2c: eval v12 — half-chunk LDS, natural register budget ----------
__global__ __launch_bounds__(256)
void vq_eval(const float* __restrict__ z, const float* __restrict__ e,
             const float* __restrict__ sz_arr, const float* __restrict__ se_arr,
             const unsigned int* __restrict__ counts, const int* __restrict__ cand,
             unsigned long long* __restrict__ packed)
{
    __shared__ float el[64 * ELS];       // 17408 B: half-chunk (64 j-rows)

    const int ch   = blockIdx.x;         // 0..63
    const int half = blockIdx.y;         // 0..1
    const int grp  = blockIdx.z;         // 0..EVG-1
    const int t    = threadIdx.x, lane = t & 63, w = t >> 6;

    const unsigned int cnt = counts[ch];
    const int base0 = grp * 16;
    if ((unsigned int)base0 >= cnt) return;

    {   // stage half-chunk: 64 rows x 64 f, coalesced float4 -> b128 LDS writes
        const float4* src4 = (const float4*)(e + (size_t)(ch * BN + half * 64) * D);
        #pragma unroll
        for (int v = t; v < 64 * D / 4; v += 256) {
            const int row = v >> 4, c4 = (v & 15) << 2;
            *(float4*)&el[row * ELS + c4] = src4[v];
        }
    }
    __syncthreads();   // only barrier; el read-only afterwards

    const int j   = ch * BN + half * 64 + lane;   // this lane's codeword
    const float* e0 = &el[lane * ELS];
    const float se0 = se_arr[j];
    const int gsrc  = lane & 15;                  // granule this lane sources
    const int isrc  = lane >> 4;                  // item this lane sources (0..3)

    for (unsigned int s0 = (unsigned int)(base0 + w * 4); s0 < cnt; s0 += (unsigned int)EVG * 16u) {
        int rows[4]; float szs[4];
        #pragma unroll
        for (int it = 0; it < 4; ++it) {
            unsigned int si = s0 + it; if (si >= cnt) si = cnt - 1;   // dup: idempotent
            rows[it] = cand[(size_t)ch * CAND_CAP + si];   // uniform -> s_load
            szs[it]  = sz_arr[rows[it]];                   // uniform -> s_load
        }
        const float4 zf = *(const float4*)(z + (size_t)rows[isrc] * D + gsrc * 4);

        float acc[4][4];   // [item][q] — 16 static accumulators
        #pragma unroll
        for (int it = 0; it < 4; ++it)
            #pragma unroll
            for (int q = 0; q < 4; ++q) acc[it][q] = 0.f;

        // frozen order: cc ascending; granules +12,+8,+4,+0; q_i gets k===i mod 4
        #pragma unroll
        for (int cc = 0; cc < 4; ++cc) {
            #pragma unroll
            for (int sb = 3; sb >= 0; --sb) {
                const int b = cc * 16 + sb * 4;
                const int g = cc * 4 + sb;
                const float4 ef = *(const float4*)&e0[b];   // ds_read_b128
                #pragma unroll
                for (int it = 0; it < 4; ++it) {
                    const int sl = it * 16 + g;             // compile-time lane
                    acc[it][0] = __fadd_rn(acc[it][0], __fmul_rn(RL(zf.x, sl), ef.x));
                    acc[it][1] = __fadd_rn(acc[it][1], __fmul_rn(RL(zf.y, sl), ef.y));
                    acc[it][2] = __fadd_rn(acc[it][2], __fmul_rn(RL(zf.z, sl), ef.z));
                    acc[it][3] = __fadd_rn(acc[it][3], __fmul_rn(RL(zf.w, sl), ef.w));
                }
            }
        }

        #pragma unroll
        for (int it = 0; it < 4; ++it) {
            const float c = __fadd_rn(__fadd_rn(acc[it][0], acc[it][1]),
                                      __fadd_rn(acc[it][2], acc[it][3]));
            const float A = __fadd_rn(szs[it], se0);           // fl(sz + se)
            float d  = __fsub_rn(A, __fadd_rn(c, c));          // fl(A - 2c)
            int   bj = j;
            #pragma unroll
            for (int o = 1; o < 64; o <<= 1) {                 // argmin, first-index ties
                const float od = __shfl_xor(d, o, 64);
                const int   oj = __shfl_xor(bj, o, 64);
                if (od < d || (od == d && oj < bj)) { d = od; bj = oj; }
            }
            if (lane == 0) {
                const unsigned long long key =
                    ((unsigned long long)__float_as_uint(d) << 32) | (unsigned int)bj;
                atomicMin(packed + rows[it], key);   // d>0 -> monotone; order-invariant
            }
        }
    }
}

// ---------- phase 3: z_q + idx from packed ----------
__global__ __launch_bounds__(256)
void vq_zq(const float* __restrict__ z, const float* __restrict__ e,
           const unsigned long long* __restrict__ packed, float* __restrict__ out)
{
    const size_t m = (size_t)blockIdx.x * 256 + threadIdx.x;
    const int r = (int)(m >> 6), k = (int)(m & 63);
    const int sel = (int)(packed[r] & 0xFFFFFFFFull);
    const float zv = z[m];
    const float ev = e[(size_t)sel * D + k];
    out[m] = __fadd_rn(zv, __fsub_rn(ev, zv));
    if (k == 0) out[(size_t)NROWS * D + r] = (float)sel;
}

extern "C" void kernel_launch(void* const* d_in, const int* in_sizes, int n_in,
                              void* d_out, int out_size, void* d_ws, size_t ws_size,
                              hipStream_t stream)
{
    const float* z = (const float*)d_in[0];
    const float* e = (const float*)d_in[1];
    float* out = (float*)d_out;

    char* ws = (char*)d_ws;
    const size_t MB = 1024 * 1024, KB = 1024;
    uint16_t* zb               = (uint16_t*)(ws);                         // 0..2 MB
    uint16_t* eb               = (uint16_t*)(ws + 2 * MB);                // 2..3 MB
    float* cmaxb               = (float*)(ws + 3 * MB);                   // 3..7 MB
    float* sz_arr              = (float*)(ws + 7 * MB);                   // 64 KB
    float* se_arr              = (float*)(ws + 7 * MB + 64 * KB);         // 32 KB
    unsigned long long* mask   = (unsigned long long*)(ws + 7 * MB + 128 * KB); // 128 KB
    unsigned long long* packed = (unsigned long long*)(ws + 7 * MB + 256 * KB); // 128 KB
    unsigned int* counts       = (unsigned int*)(ws + 7 * MB + 384 * KB); // 256 B
    int* cand                  = (int*)(ws + 8 * MB);                     // 8..12 MB

    vq_convert_prep<<<dim3(1536),            dim3(256), 0, stream>>>(z, e, (uint32_t*)zb, (uint32_t*)eb, sz_arr, se_arr);
    vq_scan_mfma   <<<dim3(2048),            dim3(256), 0, stream>>>(zb, eb, cmaxb);
    vq_select_mask <<<dim3(NROWS / 4),       dim3(256), 0, stream>>>(cmaxb, mask, packed);
    vq_compact     <<<dim3(NCH),             dim3(256), 0, stream>>>(mask, cand, counts);
    vq_eval        <<<dim3(NCH, 2, EVG),     dim3(256), 0, stream>>>(z, e, sz_arr, se_arr, counts, cand, packed);
    vq_zq          <<<dim3(NROWS * D / 256), dim3(256), 0, stream>>>(z, e, packed, out);
}